// Round 9
// baseline (147.911 us; speedup 1.0000x reference)
//
#include <hip/hip_runtime.h>
#include <hip/hip_fp16.h>
#include <stdint.h>

// ---------------------------------------------------------------------------
// ThreeBodyLayer fused kernel v8 (MI355X / gfx950)
//
// All-f16 MFMA pipeline, log2-domain softplus. Scale algebra: W1/b1 carry
// log2(e); W2 carries ln2*log2(e)=1; b2*log2(e); W3*ln2.
//
// v8 vs v7 (42.2us, VALU 48%):
//  - u-row folded into T: T[lig]=a+u/2, T[6+lig]=b+u/2 (u recomputed per
//    Phase-1 wave via 2 extra MFMAs). Phase-2 h1: s = rowA + rowB (1 add).
//  - b2 folded into layer-2 MFMA C-init; msk premultiplied into w3.
//  - explicit 1-deep ds_read prefetch across the 4 Phase-2 units (freed
//    VGPRs make 2 units' data live simultaneously).
//  - T = 12 rows, stride 1552; LDS 77.4 KB -> 2 blocks/CU kept.
// ---------------------------------------------------------------------------

typedef __attribute__((ext_vector_type(8))) _Float16 f16x8;
typedef __attribute__((ext_vector_type(2))) __fp16   fp16v2;   // cvt_pkrtz ret
typedef __attribute__((ext_vector_type(4))) float    f32x4;
typedef __attribute__((ext_vector_type(4))) unsigned int u32x4;

constexpr int   BPB       = 32;       // batch elems per block
constexpr int   NT        = 1024;     // 16 waves
constexpr int   T_STRIDE  = 1552;     // 12*128 + 16 pad; 388 words (%32==4)
constexpr int   WT_RS     = 72;       // padded f16 row stride in LDS
constexpr int   WT_OFF    = BPB * T_STRIDE;           // 49664
constexpr int   Y_OFF     = WT_OFF + 192 * WT_RS * 2; // 77312
constexpr int   LDS_BYTES = Y_OFF + 128;              // 77440 -> 2 blocks/CU

// d_ws layout (bytes)
constexpr int   WS_W1T   = 0;         // 12288 f16 compact: (slab*64+n)*64 + d
constexpr int   WS_W2T   = 24576;     //  2048 f16 : m*64 + k
constexpr int   WS_B1    = 28672;     //    64 f32 : b1 * L2E
constexpr int   WS_B2    = 28928;     //    32 f32 : b2 * L2E
constexpr int   WS_W3    = 29056;     //    32 f32 : W3 * LN2
constexpr int   WS_BYTES = 29184;

constexpr float L2E = 1.4426950408889634f;
constexpr float LN2 = 0.6931471805599453f;

// PAIRS i/j packed 3 bits per pair (15 pairs; shift 45 yields 0 -> safe)
constexpr unsigned long long I_BITS =
  (0ull<<0)|(0ull<<3)|(0ull<<6)|(0ull<<9)|(0ull<<12)|
  (1ull<<15)|(1ull<<18)|(1ull<<21)|(1ull<<24)|
  (2ull<<27)|(2ull<<30)|(2ull<<33)|
  (3ull<<36)|(3ull<<39)|(4ull<<42);
constexpr unsigned long long J_BITS =
  (1ull<<0)|(2ull<<3)|(3ull<<6)|(4ull<<9)|(5ull<<12)|
  (2ull<<15)|(3ull<<18)|(4ull<<21)|(5ull<<24)|
  (3ull<<27)|(4ull<<30)|(5ull<<33)|
  (4ull<<36)|(5ull<<39)|(5ull<<42);

__device__ __forceinline__ float sp2(float s) {       // log2(1+exp2(s))
  float t = __builtin_amdgcn_exp2f(s);
  return __builtin_amdgcn_logf(1.0f + t);             // v_log_f32 = log2
}

// h1 for TWO values: s = a + b (u already folded into both rows)
__device__ __forceinline__ __half2 h1pair(__half2 a, __half2 b, __half2 one2) {
  __half2 t = h2exp2(__hadd2(a, b));
  return h2log2(__hadd2(one2, t));
}

// ------------------------- prep: weights -> d_ws ---------------------------
__global__ __launch_bounds__(256)
void prep(const float* __restrict__ W1, const float* __restrict__ b1,
          const float* __restrict__ W2, const float* __restrict__ b2,
          const float* __restrict__ W3, char* __restrict__ ws)
{
  const int t = (int)(blockIdx.x * blockDim.x + threadIdx.x);   // 0..16383
  uint16_t* w1t = (uint16_t*)(ws + WS_W1T);
  uint16_t* w2t = (uint16_t*)(ws + WS_W2T);
  float*    b1s = (float*)(ws + WS_B1);
  float*    b2s = (float*)(ws + WS_B2);
  float*    w3s = (float*)(ws + WS_W3);
  if (t < 12288) {
    const int d = t >> 6, n = t & 63;                 // W1 is [d=192][n=64]
    const int slab = d >> 6;
    w1t[(slab * 64 + n) * 64 + (d & 63)] =
        __half_as_ushort(__float2half(W1[t] * L2E));
  } else if (t < 14336) {
    const int e = t - 12288;                          // W2 is [k=64][m=32]
    const int k = e >> 5, m = e & 31;
    w2t[m * 64 + k] = __half_as_ushort(__float2half(W2[e]));
  } else if (t < 14400) {
    b1s[t - 14336] = b1[t - 14336] * L2E;
  } else if (t < 14432) {
    b2s[t - 14400] = b2[t - 14400] * L2E;
  } else if (t < 14464) {
    w3s[t - 14432] = W3[t - 14432] * LN2;
  }
}

// ------------------------------ main kernel --------------------------------
__global__ __launch_bounds__(NT, 8)
void tb_fused(const float* __restrict__ core, const float* __restrict__ ligs,
              const float* __restrict__ b3,   const char* __restrict__ ws,
              float* __restrict__ out)
{
  extern __shared__ char smem[];
  const int tid  = (int)threadIdx.x;
  const int lane = tid & 63;
  const int ln   = lane & 15;        // fragment column
  const int qd   = lane >> 4;        // fragment quad
  const int wv   = __builtin_amdgcn_readfirstlane(tid >> 6);  // 0..15
  const int b0   = (int)blockIdx.x * BPB;

  const uint16_t* w2t = (const uint16_t*)(ws + WS_W2T);
  const float*    b1s = (const float*)(ws + WS_B1);
  const float*    b2s = (const float*)(ws + WS_B2);
  const float*    w3s = (const float*)(ws + WS_W3);

  float* yred = (float*)(smem + Y_OFF);

  // ---- stage W1T (compact ws rows of 64 halves -> LDS rows of stride 72) --
  #pragma unroll
  for (int rep = 0; rep < 3; ++rep) {
    const int c   = tid + rep * NT;                   // < 3072 always
    const int row = c >> 4, col = c & 15;
    *(uint2*)(smem + WT_OFF + row * (WT_RS * 2) + col * 8) =
        *(const uint2*)(ws + WS_W1T + row * 128 + col * 8);
  }
  if (tid < BPB) yred[tid] = 0.0f;
  __syncthreads();                                    // barrier #1: W1T ready

  // ------------- Phase 1: 12 jobs = (lig 0..5) x (mt 0..1), 1 per wave ----
  // T[lig] = lig@W1slab1 + u/2 ; T[6+lig] = lig@W1slab2 + u/2
  // where u = core@W1slab0 + b1 (recomputed per wave; MFMA pipe is idle).
  if (wv < 12) {
    const int lg = wv >> 1;
    const int mt = wv & 1;
    const float* srcC = core + (size_t)(b0 + mt * 16 + ln) * 64;
    const float* srcL = ligs + ((size_t)(b0 + mt * 16 + ln) * 6 + (size_t)lg) * 64;

    union AF { f16x8 v; fp16v2 p[4]; } Ac[2], Al[2];
    #pragma unroll
    for (int ks = 0; ks < 2; ++ks) {
      const float4 c0 = *(const float4*)(srcC + ks * 32 + qd * 8);
      const float4 c1 = *(const float4*)(srcC + ks * 32 + qd * 8 + 4);
      Ac[ks].p[0] = __builtin_amdgcn_cvt_pkrtz(c0.x, c0.y);
      Ac[ks].p[1] = __builtin_amdgcn_cvt_pkrtz(c0.z, c0.w);
      Ac[ks].p[2] = __builtin_amdgcn_cvt_pkrtz(c1.x, c1.y);
      Ac[ks].p[3] = __builtin_amdgcn_cvt_pkrtz(c1.z, c1.w);
      const float4 l0 = *(const float4*)(srcL + ks * 32 + qd * 8);
      const float4 l1 = *(const float4*)(srcL + ks * 32 + qd * 8 + 4);
      Al[ks].p[0] = __builtin_amdgcn_cvt_pkrtz(l0.x, l0.y);
      Al[ks].p[1] = __builtin_amdgcn_cvt_pkrtz(l0.z, l0.w);
      Al[ks].p[2] = __builtin_amdgcn_cvt_pkrtz(l1.x, l1.y);
      Al[ks].p[3] = __builtin_amdgcn_cvt_pkrtz(l1.z, l1.w);
    }

    #pragma unroll
    for (int nt = 0; nt < 4; ++nt) {
      const float b1v = b1s[nt * 16 + ln];
      f32x4 cu = {b1v, b1v, b1v, b1v};
      f32x4 ca = {0.f, 0.f, 0.f, 0.f};
      f32x4 cb = {0.f, 0.f, 0.f, 0.f};
      #pragma unroll
      for (int ks = 0; ks < 2; ++ks) {
        const int rb = (nt * 16 + ln) * WT_RS + ks * 32 + qd * 8;
        const f16x8 B0 = *(const f16x8*)(smem + WT_OFF + (rb           ) * 2);
        const f16x8 B1 = *(const f16x8*)(smem + WT_OFF + (rb + 64*WT_RS) * 2);
        const f16x8 B2 = *(const f16x8*)(smem + WT_OFF + (rb +128*WT_RS) * 2);
        cu = __builtin_amdgcn_mfma_f32_16x16x32_f16(Ac[ks].v, B0, cu, 0, 0, 0);
        ca = __builtin_amdgcn_mfma_f32_16x16x32_f16(Al[ks].v, B1, ca, 0, 0, 0);
        cb = __builtin_amdgcn_mfma_f32_16x16x32_f16(Al[ks].v, B2, cb, 0, 0, 0);
      }
      #pragma unroll
      for (int reg = 0; reg < 4; ++reg) {
        const int b = mt * 16 + qd * 4 + reg;         // C row = batch-local b
        const float uh = 0.5f * cu[reg];
        char* Tbb = smem + (size_t)b * T_STRIDE + (nt * 16 + ln) * 2;
        *(uint16_t*)(Tbb + lg * 128)       = __half_as_ushort(__float2half(ca[reg] + uh));
        *(uint16_t*)(Tbb + (6 + lg) * 128) = __half_as_ushort(__float2half(cb[reg] + uh));
      }
    }
  }

  // W2 B-frags + epilogue consts (global, L2-hot) — overlaps Phase-1 tail
  f16x8 W2f[2][2];
  #pragma unroll
  for (int nt = 0; nt < 2; ++nt)
    #pragma unroll
    for (int ks = 0; ks < 2; ++ks)
      W2f[nt][ks] = *(const f16x8*)(w2t + (nt * 16 + ln) * 64 + ks * 32 + qd * 8);
  float b2v[2], w3v[2];
  #pragma unroll
  for (int nt = 0; nt < 2; ++nt) {
    b2v[nt] = b2s[nt * 16 + ln];
    w3v[nt] = w3s[nt * 16 + ln];
  }

  __syncthreads();                                    // barrier #2: T ready

  // ------------- Phase 2: 60 units (30 q x 2 mt) over 16 waves ------------
  const int mtw = wv & 1;
  const int qr  = wv >> 1;                            // 0..7
  const __half2 one2 = __float2half2_rn(1.0f);
  const char* Tb  = smem + (size_t)(mtw * 16 + ln) * T_STRIDE;
  const int koff  = qd * 16;

  float yacc[4] = {0.f, 0.f, 0.f, 0.f};

  union U4 { u32x4 u; __half2 h[4]; };

  // decode all 4 units up front (scalar)
  int rowA[4], rowB[4];
  float msk[4];
  #pragma unroll
  for (int t3 = 0; t3 < 4; ++t3) {
    const int q = qr + 8 * t3;
    msk[t3] = (q < 30) ? 1.0f : 0.0f;
    const int p  = q >> 1;
    const int iv = (int)((I_BITS >> (3 * p)) & 7ull);
    const int jv = (int)((J_BITS >> (3 * p)) & 7ull);
    rowA[t3] = ((q & 1) ? jv : iv) * 128;
    rowB[t3] = (6 + ((q & 1) ? iv : jv)) * 128;
  }

  auto loadu = [&](int t3, U4& a0, U4& a1, U4& bb0, U4& bb1) {
    a0.u  = *(const u32x4*)(Tb + rowA[t3] + koff);
    a1.u  = *(const u32x4*)(Tb + rowA[t3] + 64 + koff);
    bb0.u = *(const u32x4*)(Tb + rowB[t3] + koff);
    bb1.u = *(const u32x4*)(Tb + rowB[t3] + 64 + koff);
  };

  auto compute = [&](const U4& a0, const U4& a1, const U4& bb0, const U4& bb1,
                     float m) {
    union { f16x8 v; __half2 h[4]; } A0, A1;
    #pragma unroll
    for (int w = 0; w < 4; ++w) A0.h[w] = h1pair(a0.h[w], bb0.h[w], one2);
    #pragma unroll
    for (int w = 0; w < 4; ++w) A1.h[w] = h1pair(a1.h[w], bb1.h[w], one2);
    f32x4 c0 = {b2v[0], b2v[0], b2v[0], b2v[0]};      // b2 folded into C-init
    f32x4 c1 = {b2v[1], b2v[1], b2v[1], b2v[1]};
    c0 = __builtin_amdgcn_mfma_f32_16x16x32_f16(A0.v, W2f[0][0], c0, 0, 0, 0);
    c0 = __builtin_amdgcn_mfma_f32_16x16x32_f16(A1.v, W2f[0][1], c0, 0, 0, 0);
    c1 = __builtin_amdgcn_mfma_f32_16x16x32_f16(A0.v, W2f[1][0], c1, 0, 0, 0);
    c1 = __builtin_amdgcn_mfma_f32_16x16x32_f16(A1.v, W2f[1][1], c1, 0, 0, 0);
    const float w3m0 = w3v[0] * m;
    const float w3m1 = w3v[1] * m;
    #pragma unroll
    for (int reg = 0; reg < 4; ++reg)
      yacc[reg] += sp2(c0[reg]) * w3m0 + sp2(c1[reg]) * w3m1;
  };

  // software pipeline: L0 L1 C0 L2 C1 L3 C2 C3
  U4 pa0, pa1, pb0, pb1, na0, na1, nb0, nb1;
  loadu(0, pa0, pa1, pb0, pb1);
  loadu(1, na0, na1, nb0, nb1);
  compute(pa0, pa1, pb0, pb1, msk[0]);
  loadu(2, pa0, pa1, pb0, pb1);
  compute(na0, na1, nb0, nb1, msk[1]);
  loadu(3, na0, na1, nb0, nb1);
  compute(pa0, pa1, pb0, pb1, msk[2]);
  compute(na0, na1, nb0, nb1, msk[3]);

  // reduce over the 16 fragment columns (ln) inside each quad group
  #pragma unroll
  for (int reg = 0; reg < 4; ++reg) {
    float v = yacc[reg];
    v += __shfl_xor(v, 1);
    v += __shfl_xor(v, 2);
    v += __shfl_xor(v, 4);
    v += __shfl_xor(v, 8);
    yacc[reg] = v;
  }
  if (ln == 0) {
    #pragma unroll
    for (int reg = 0; reg < 4; ++reg)
      atomicAdd(&yred[mtw * 16 + qd * 4 + reg], yacc[reg]);
  }
  __syncthreads();
  if (tid < BPB) out[b0 + tid] = 0.5f * yred[tid] + 15.0f * b3[0];
}

extern "C" void kernel_launch(void* const* d_in, const int* in_sizes, int n_in,
                              void* d_out, int out_size, void* d_ws, size_t ws_size,
                              hipStream_t stream) {
  const float* core = (const float*)d_in[0];
  const float* ligs = (const float*)d_in[1];
  const float* W1   = (const float*)d_in[2];
  const float* b1   = (const float*)d_in[3];
  const float* W2   = (const float*)d_in[4];
  const float* b2   = (const float*)d_in[5];
  const float* W3   = (const float*)d_in[6];
  const float* b3   = (const float*)d_in[7];
  float* out = (float*)d_out;
  char*  ws  = (char*)d_ws;                 // needs WS_BYTES (29 KB) scratch

  const int B = in_sizes[0] / 64;           // 32768
  const int grid = B / BPB;                 // 1024

  prep<<<dim3(57), dim3(256), 0, stream>>>(W1, b1, W2, b2, W3, ws);

  (void)hipFuncSetAttribute((const void*)tb_fused,
                            hipFuncAttributeMaxDynamicSharedMemorySize, LDS_BYTES);
  tb_fused<<<dim3(grid), dim3(NT), LDS_BYTES, stream>>>(
      core, ligs, b3, ws, out);
}

// Round 10
// 146.955 us; speedup vs baseline: 1.0065x; 1.0065x over previous
//
#include <hip/hip_runtime.h>
#include <hip/hip_fp16.h>
#include <stdint.h>

// ---------------------------------------------------------------------------
// ThreeBodyLayer fused kernel v9 (MI355X / gfx950)
//
// All-f16 MFMA pipeline, log2-domain softplus. Scale algebra: W1/b1 carry
// log2(e); W2 carries ln2*log2(e)=1; b2*log2(e); W3*ln2.
//
// v9 = v7 skeleton (42.2us; per-iter loads, compiler-scheduled, no spill)
//   + v8's u-folding (T[lig]=a+u/2, T[6+lig]=b+u/2; Phase-2 h1 = 1 add)
//   + v8's b2-in-C-init
//   + NEW packed-f16 epilogue: pack(c0,c1) -> h2exp2/hadd2/h2log2 -> fdot2
//     against half2(w3*msk); halves epilogue transcendentals.
// v8's explicit 2-unit prefetch REVERTED: it spilled (WRITE_SIZE 86MB) at
// the 64-VGPR/8-wave budget and regressed to 61us.
// ---------------------------------------------------------------------------

typedef __attribute__((ext_vector_type(8))) _Float16 f16x8;
typedef __attribute__((ext_vector_type(2))) _Float16 f16x2;
typedef __attribute__((ext_vector_type(2))) __fp16   fp16v2;   // cvt_pkrtz ret
typedef __attribute__((ext_vector_type(4))) float    f32x4;
typedef __attribute__((ext_vector_type(4))) unsigned int u32x4;

constexpr int   BPB       = 32;       // batch elems per block
constexpr int   NT        = 1024;     // 16 waves
constexpr int   T_STRIDE  = 1552;     // 12*128 + 16 pad
constexpr int   WT_RS     = 72;       // padded f16 row stride in LDS
constexpr int   WT_OFF    = BPB * T_STRIDE;           // 49664
constexpr int   Y_OFF     = WT_OFF + 192 * WT_RS * 2; // 77312
constexpr int   LDS_BYTES = Y_OFF + 128;              // 77440 -> 2 blocks/CU

// d_ws layout (bytes)
constexpr int   WS_W1T   = 0;         // 12288 f16 compact: (slab*64+n)*64 + d
constexpr int   WS_W2T   = 24576;     //  2048 f16 : m*64 + k
constexpr int   WS_B1    = 28672;     //    64 f32 : b1 * L2E
constexpr int   WS_B2    = 28928;     //    32 f32 : b2 * L2E
constexpr int   WS_W3    = 29056;     //    32 f32 : W3 * LN2
constexpr int   WS_BYTES = 29184;

constexpr float L2E = 1.4426950408889634f;
constexpr float LN2 = 0.6931471805599453f;

// PAIRS i/j packed 3 bits per pair (15 pairs; shift 45 yields 0 -> safe)
constexpr unsigned long long I_BITS =
  (0ull<<0)|(0ull<<3)|(0ull<<6)|(0ull<<9)|(0ull<<12)|
  (1ull<<15)|(1ull<<18)|(1ull<<21)|(1ull<<24)|
  (2ull<<27)|(2ull<<30)|(2ull<<33)|
  (3ull<<36)|(3ull<<39)|(4ull<<42);
constexpr unsigned long long J_BITS =
  (1ull<<0)|(2ull<<3)|(3ull<<6)|(4ull<<9)|(5ull<<12)|
  (2ull<<15)|(3ull<<18)|(4ull<<21)|(5ull<<24)|
  (3ull<<27)|(4ull<<30)|(5ull<<33)|
  (4ull<<36)|(5ull<<39)|(5ull<<42);

// h1 for TWO values: s = a + b (u already folded into both rows)
__device__ __forceinline__ __half2 h1pair(__half2 a, __half2 b, __half2 one2) {
  __half2 t = h2exp2(__hadd2(a, b));
  return h2log2(__hadd2(one2, t));
}

// packed log2-softplus of (x,y) -> half2
__device__ __forceinline__ __half2 sp2pk(float x, float y, __half2 one2) {
  union { fp16v2 p; __half2 h; } s;
  s.p = __builtin_amdgcn_cvt_pkrtz(x, y);
  __half2 t = h2exp2(s.h);
  return h2log2(__hadd2(one2, t));
}

// f32 += a.x*b.x + a.y*b.y  (v_dot2_f32_f16)
__device__ __forceinline__ float dot2(__half2 a, __half2 b, float c) {
  union { __half2 h; f16x2 v; } ua, ub;
  ua.h = a; ub.h = b;
  return __builtin_amdgcn_fdot2(ua.v, ub.v, c, false);
}

// ------------------------- prep: weights -> d_ws ---------------------------
__global__ __launch_bounds__(256)
void prep(const float* __restrict__ W1, const float* __restrict__ b1,
          const float* __restrict__ W2, const float* __restrict__ b2,
          const float* __restrict__ W3, char* __restrict__ ws)
{
  const int t = (int)(blockIdx.x * blockDim.x + threadIdx.x);   // 0..16383
  uint16_t* w1t = (uint16_t*)(ws + WS_W1T);
  uint16_t* w2t = (uint16_t*)(ws + WS_W2T);
  float*    b1s = (float*)(ws + WS_B1);
  float*    b2s = (float*)(ws + WS_B2);
  float*    w3s = (float*)(ws + WS_W3);
  if (t < 12288) {
    const int d = t >> 6, n = t & 63;                 // W1 is [d=192][n=64]
    const int slab = d >> 6;
    w1t[(slab * 64 + n) * 64 + (d & 63)] =
        __half_as_ushort(__float2half(W1[t] * L2E));
  } else if (t < 14336) {
    const int e = t - 12288;                          // W2 is [k=64][m=32]
    const int k = e >> 5, m = e & 31;
    w2t[m * 64 + k] = __half_as_ushort(__float2half(W2[e]));
  } else if (t < 14400) {
    b1s[t - 14336] = b1[t - 14336] * L2E;
  } else if (t < 14432) {
    b2s[t - 14400] = b2[t - 14400] * L2E;
  } else if (t < 14464) {
    w3s[t - 14432] = W3[t - 14432] * LN2;
  }
}

// ------------------------------ main kernel --------------------------------
__global__ __launch_bounds__(NT, 8)
void tb_fused(const float* __restrict__ core, const float* __restrict__ ligs,
              const float* __restrict__ b3,   const char* __restrict__ ws,
              float* __restrict__ out)
{
  extern __shared__ char smem[];
  const int tid  = (int)threadIdx.x;
  const int lane = tid & 63;
  const int ln   = lane & 15;        // fragment column
  const int qd   = lane >> 4;        // fragment quad
  const int wv   = __builtin_amdgcn_readfirstlane(tid >> 6);  // 0..15
  const int b0   = (int)blockIdx.x * BPB;

  const uint16_t* w2t = (const uint16_t*)(ws + WS_W2T);
  const float*    b1s = (const float*)(ws + WS_B1);
  const float*    b2s = (const float*)(ws + WS_B2);
  const float*    w3s = (const float*)(ws + WS_W3);

  float* yred = (float*)(smem + Y_OFF);

  // ---- stage W1T (compact ws rows of 64 halves -> LDS rows of stride 72) --
  #pragma unroll
  for (int rep = 0; rep < 3; ++rep) {
    const int c   = tid + rep * NT;                   // < 3072 always
    const int row = c >> 4, col = c & 15;
    *(uint2*)(smem + WT_OFF + row * (WT_RS * 2) + col * 8) =
        *(const uint2*)(ws + WS_W1T + row * 128 + col * 8);
  }
  if (tid < BPB) yred[tid] = 0.0f;
  __syncthreads();                                    // barrier #1: W1T ready

  // ------------- Phase 1: 12 jobs = (lig 0..5) x (mt 0..1), 1 per wave ----
  // T[lig] = lig@W1slab1 + u/2 ; T[6+lig] = lig@W1slab2 + u/2,
  // u = core@W1slab0 + b1 (recomputed per wave; MFMA pipe is near-idle).
  if (wv < 12) {
    const int lg = wv >> 1;
    const int mt = wv & 1;
    const float* srcC = core + (size_t)(b0 + mt * 16 + ln) * 64;
    const float* srcL = ligs + ((size_t)(b0 + mt * 16 + ln) * 6 + (size_t)lg) * 64;

    union AF { f16x8 v; fp16v2 p[4]; } Ac[2], Al[2];
    #pragma unroll
    for (int ks = 0; ks < 2; ++ks) {
      const float4 c0 = *(const float4*)(srcC + ks * 32 + qd * 8);
      const float4 c1 = *(const float4*)(srcC + ks * 32 + qd * 8 + 4);
      Ac[ks].p[0] = __builtin_amdgcn_cvt_pkrtz(c0.x, c0.y);
      Ac[ks].p[1] = __builtin_amdgcn_cvt_pkrtz(c0.z, c0.w);
      Ac[ks].p[2] = __builtin_amdgcn_cvt_pkrtz(c1.x, c1.y);
      Ac[ks].p[3] = __builtin_amdgcn_cvt_pkrtz(c1.z, c1.w);
      const float4 l0 = *(const float4*)(srcL + ks * 32 + qd * 8);
      const float4 l1 = *(const float4*)(srcL + ks * 32 + qd * 8 + 4);
      Al[ks].p[0] = __builtin_amdgcn_cvt_pkrtz(l0.x, l0.y);
      Al[ks].p[1] = __builtin_amdgcn_cvt_pkrtz(l0.z, l0.w);
      Al[ks].p[2] = __builtin_amdgcn_cvt_pkrtz(l1.x, l1.y);
      Al[ks].p[3] = __builtin_amdgcn_cvt_pkrtz(l1.z, l1.w);
    }

    #pragma unroll
    for (int nt = 0; nt < 4; ++nt) {
      const float b1v = b1s[nt * 16 + ln];
      f32x4 cu = {b1v, b1v, b1v, b1v};
      f32x4 ca = {0.f, 0.f, 0.f, 0.f};
      f32x4 cb = {0.f, 0.f, 0.f, 0.f};
      #pragma unroll
      for (int ks = 0; ks < 2; ++ks) {
        const int rb = (nt * 16 + ln) * WT_RS + ks * 32 + qd * 8;
        const f16x8 B0 = *(const f16x8*)(smem + WT_OFF + (rb           ) * 2);
        const f16x8 B1 = *(const f16x8*)(smem + WT_OFF + (rb + 64*WT_RS) * 2);
        const f16x8 B2 = *(const f16x8*)(smem + WT_OFF + (rb +128*WT_RS) * 2);
        cu = __builtin_amdgcn_mfma_f32_16x16x32_f16(Ac[ks].v, B0, cu, 0, 0, 0);
        ca = __builtin_amdgcn_mfma_f32_16x16x32_f16(Al[ks].v, B1, ca, 0, 0, 0);
        cb = __builtin_amdgcn_mfma_f32_16x16x32_f16(Al[ks].v, B2, cb, 0, 0, 0);
      }
      #pragma unroll
      for (int reg = 0; reg < 4; ++reg) {
        const int b = mt * 16 + qd * 4 + reg;         // C row = batch-local b
        const float uh = 0.5f * cu[reg];
        char* Tbb = smem + (size_t)b * T_STRIDE + (nt * 16 + ln) * 2;
        *(uint16_t*)(Tbb + lg * 128)       = __half_as_ushort(__float2half(ca[reg] + uh));
        *(uint16_t*)(Tbb + (6 + lg) * 128) = __half_as_ushort(__float2half(cb[reg] + uh));
      }
    }
  }

  // W2 B-frags + epilogue consts (global, L2-hot) — overlaps Phase-1 tail
  f16x8 W2f[2][2];
  #pragma unroll
  for (int nt = 0; nt < 2; ++nt)
    #pragma unroll
    for (int ks = 0; ks < 2; ++ks)
      W2f[nt][ks] = *(const f16x8*)(w2t + (nt * 16 + ln) * 64 + ks * 32 + qd * 8);
  float b2v[2];
  b2v[0] = b2s[ln];
  b2v[1] = b2s[16 + ln];
  __half2 w3pk = __floats2half2_rn(w3s[ln], w3s[16 + ln]);   // (w3' m=ln, m=16+ln)

  __syncthreads();                                    // barrier #2: T ready

  // ------------- Phase 2: 60 units (30 q x 2 mt) over 16 waves ------------
  const int mtw = wv & 1;
  const int qr  = wv >> 1;                            // 0..7
  const __half2 one2  = __float2half2_rn(1.0f);
  const __half2 zero2 = __float2half2_rn(0.0f);
  const char* Tb  = smem + (size_t)(mtw * 16 + ln) * T_STRIDE;
  const int koff  = qd * 16;

  union U4 { u32x4 u; __half2 h[4]; };
  float yacc[4] = {0.f, 0.f, 0.f, 0.f};

  #pragma unroll
  for (int t3 = 0; t3 < 4; ++t3) {
    const int q = qr + 8 * t3;                        // <= 31
    const __half2 w3h = (q < 30) ? w3pk : zero2;      // wave-uniform mask
    const int p  = q >> 1;
    const int iv = (int)((I_BITS >> (3 * p)) & 7ull); // p=15 -> 0 (safe)
    const int jv = (int)((J_BITS >> (3 * p)) & 7ull);
    const int rA = ((q & 1) ? jv : iv) * 128;
    const int rB = (6 + ((q & 1) ? iv : jv)) * 128;

    U4 a0, a1, bb0, bb1;
    a0.u  = *(const u32x4*)(Tb + rA + koff);
    a1.u  = *(const u32x4*)(Tb + rA + 64 + koff);
    bb0.u = *(const u32x4*)(Tb + rB + koff);
    bb1.u = *(const u32x4*)(Tb + rB + 64 + koff);

    union { f16x8 v; __half2 h[4]; } A0, A1;
    #pragma unroll
    for (int w = 0; w < 4; ++w) A0.h[w] = h1pair(a0.h[w], bb0.h[w], one2);
    #pragma unroll
    for (int w = 0; w < 4; ++w) A1.h[w] = h1pair(a1.h[w], bb1.h[w], one2);

    f32x4 c0 = {b2v[0], b2v[0], b2v[0], b2v[0]};      // b2 folded into C-init
    f32x4 c1 = {b2v[1], b2v[1], b2v[1], b2v[1]};
    c0 = __builtin_amdgcn_mfma_f32_16x16x32_f16(A0.v, W2f[0][0], c0, 0, 0, 0);
    c0 = __builtin_amdgcn_mfma_f32_16x16x32_f16(A1.v, W2f[0][1], c0, 0, 0, 0);
    c1 = __builtin_amdgcn_mfma_f32_16x16x32_f16(A0.v, W2f[1][0], c1, 0, 0, 0);
    c1 = __builtin_amdgcn_mfma_f32_16x16x32_f16(A1.v, W2f[1][1], c1, 0, 0, 0);

    #pragma unroll
    for (int reg = 0; reg < 4; ++reg)
      yacc[reg] = dot2(sp2pk(c0[reg], c1[reg], one2), w3h, yacc[reg]);
  }

  // reduce over the 16 fragment columns (ln) inside each quad group
  #pragma unroll
  for (int reg = 0; reg < 4; ++reg) {
    float v = yacc[reg];
    v += __shfl_xor(v, 1);
    v += __shfl_xor(v, 2);
    v += __shfl_xor(v, 4);
    v += __shfl_xor(v, 8);
    yacc[reg] = v;
  }
  if (ln == 0) {
    #pragma unroll
    for (int reg = 0; reg < 4; ++reg)
      atomicAdd(&yred[mtw * 16 + qd * 4 + reg], yacc[reg]);
  }
  __syncthreads();
  if (tid < BPB) out[b0 + tid] = 0.5f * yred[tid] + 15.0f * b3[0];
}

extern "C" void kernel_launch(void* const* d_in, const int* in_sizes, int n_in,
                              void* d_out, int out_size, void* d_ws, size_t ws_size,
                              hipStream_t stream) {
  const float* core = (const float*)d_in[0];
  const float* ligs = (const float*)d_in[1];
  const float* W1   = (const float*)d_in[2];
  const float* b1   = (const float*)d_in[3];
  const float* W2   = (const float*)d_in[4];
  const float* b2   = (const float*)d_in[5];
  const float* W3   = (const float*)d_in[6];
  const float* b3   = (const float*)d_in[7];
  float* out = (float*)d_out;
  char*  ws  = (char*)d_ws;                 // needs WS_BYTES (29 KB) scratch

  const int B = in_sizes[0] / 64;           // 32768
  const int grid = B / BPB;                 // 1024

  prep<<<dim3(57), dim3(256), 0, stream>>>(W1, b1, W2, b2, W3, ws);

  (void)hipFuncSetAttribute((const void*)tb_fused,
                            hipFuncAttributeMaxDynamicSharedMemorySize, LDS_BYTES);
  tb_fused<<<dim3(grid), dim3(NT), LDS_BYTES, stream>>>(
      core, ligs, b3, ws, out);
}

// Round 11
// 125.998 us; speedup vs baseline: 1.1739x; 1.1663x over previous
//
#include <hip/hip_runtime.h>
#include <hip/hip_fp16.h>
#include <stdint.h>

// ---------------------------------------------------------------------------
// ThreeBodyLayer fused kernel v11 (MI355X / gfx950)
//
// All-f16 MFMA pipeline, log2-domain softplus. Scale algebra: W1/b1 carry
// log2(e); W2 carries ln2*log2(e)=1; b2*log2(e); W3*ln2.
//
// v11 vs v9 (59.6us, Phase-1 register spill -> 82MB scratch WRITE):
//  - Phase 1 split into two passes so no wave ever holds 3 accumulator
//    streams: Pass A (8 waves) computes u=core@slab0+b1, stores u/2 as f16
//    into a 4KB LDS U-buffer; Pass B (12 waves) computes a/b rows with only
//    ca/cb live (unroll 2), reads uh back via ds_read_u16, stores T.
//  - Phase 2 unchanged from v9: u-folded T rows (h1 = 1 add), b2 in MFMA
//    C-init, masked-w3 fdot2 epilogue, per-iteration loads (no manual
//    prefetch -> compiler schedules within the 64-VGPR/8-wave budget).
//  - LDS 81536B (T 49664 + W1T 27648 + U 4096 + yred) -> 2 blocks/CU kept.
// ---------------------------------------------------------------------------

typedef __attribute__((ext_vector_type(8))) _Float16 f16x8;
typedef __attribute__((ext_vector_type(2))) _Float16 f16x2;
typedef __attribute__((ext_vector_type(2))) __fp16   fp16v2;   // cvt_pkrtz ret
typedef __attribute__((ext_vector_type(4))) float    f32x4;
typedef __attribute__((ext_vector_type(4))) unsigned int u32x4;

constexpr int   BPB       = 32;       // batch elems per block
constexpr int   NT        = 1024;     // 16 waves
constexpr int   T_STRIDE  = 1552;     // 12*128 + 16 pad
constexpr int   WT_RS     = 72;       // padded f16 row stride in LDS
constexpr int   WT_OFF    = BPB * T_STRIDE;           // 49664
constexpr int   U_OFF     = WT_OFF + 192 * WT_RS * 2; // 77312 (u/2, f16, [b][n])
constexpr int   Y_OFF     = U_OFF + BPB * 64 * 2;     // 81408
constexpr int   LDS_BYTES = Y_OFF + 128;              // 81536 <= 81920 -> 2 blk/CU

// d_ws layout (bytes)
constexpr int   WS_W1T   = 0;         // 12288 f16 compact: (slab*64+n)*64 + d
constexpr int   WS_W2T   = 24576;     //  2048 f16 : m*64 + k
constexpr int   WS_B1    = 28672;     //    64 f32 : b1 * L2E
constexpr int   WS_B2    = 28928;     //    32 f32 : b2 * L2E
constexpr int   WS_W3    = 29056;     //    32 f32 : W3 * LN2
constexpr int   WS_BYTES = 29184;

constexpr float L2E = 1.4426950408889634f;
constexpr float LN2 = 0.6931471805599453f;

// PAIRS i/j packed 3 bits per pair (15 pairs; shift 45 yields 0 -> safe)
constexpr unsigned long long I_BITS =
  (0ull<<0)|(0ull<<3)|(0ull<<6)|(0ull<<9)|(0ull<<12)|
  (1ull<<15)|(1ull<<18)|(1ull<<21)|(1ull<<24)|
  (2ull<<27)|(2ull<<30)|(2ull<<33)|
  (3ull<<36)|(3ull<<39)|(4ull<<42);
constexpr unsigned long long J_BITS =
  (1ull<<0)|(2ull<<3)|(3ull<<6)|(4ull<<9)|(5ull<<12)|
  (2ull<<15)|(3ull<<18)|(4ull<<21)|(5ull<<24)|
  (3ull<<27)|(4ull<<30)|(5ull<<33)|
  (4ull<<36)|(5ull<<39)|(5ull<<42);

// h1 for TWO values: s = a + b (u already folded into both rows)
__device__ __forceinline__ __half2 h1pair(__half2 a, __half2 b, __half2 one2) {
  __half2 t = h2exp2(__hadd2(a, b));
  return h2log2(__hadd2(one2, t));
}

// packed log2-softplus of (x,y) -> half2
__device__ __forceinline__ __half2 sp2pk(float x, float y, __half2 one2) {
  union { fp16v2 p; __half2 h; } s;
  s.p = __builtin_amdgcn_cvt_pkrtz(x, y);
  __half2 t = h2exp2(s.h);
  return h2log2(__hadd2(one2, t));
}

// f32 += a.x*b.x + a.y*b.y  (v_dot2_f32_f16)
__device__ __forceinline__ float dot2(__half2 a, __half2 b, float c) {
  union { __half2 h; f16x2 v; } ua, ub;
  ua.h = a; ub.h = b;
  return __builtin_amdgcn_fdot2(ua.v, ub.v, c, false);
}

// ------------------------- prep: weights -> d_ws ---------------------------
__global__ __launch_bounds__(256)
void prep(const float* __restrict__ W1, const float* __restrict__ b1,
          const float* __restrict__ W2, const float* __restrict__ b2,
          const float* __restrict__ W3, char* __restrict__ ws)
{
  const int t = (int)(blockIdx.x * blockDim.x + threadIdx.x);   // 0..16383
  uint16_t* w1t = (uint16_t*)(ws + WS_W1T);
  uint16_t* w2t = (uint16_t*)(ws + WS_W2T);
  float*    b1s = (float*)(ws + WS_B1);
  float*    b2s = (float*)(ws + WS_B2);
  float*    w3s = (float*)(ws + WS_W3);
  if (t < 12288) {
    const int d = t >> 6, n = t & 63;                 // W1 is [d=192][n=64]
    const int slab = d >> 6;
    w1t[(slab * 64 + n) * 64 + (d & 63)] =
        __half_as_ushort(__float2half(W1[t] * L2E));
  } else if (t < 14336) {
    const int e = t - 12288;                          // W2 is [k=64][m=32]
    const int k = e >> 5, m = e & 31;
    w2t[m * 64 + k] = __half_as_ushort(__float2half(W2[e]));
  } else if (t < 14400) {
    b1s[t - 14336] = b1[t - 14336] * L2E;
  } else if (t < 14432) {
    b2s[t - 14400] = b2[t - 14400] * L2E;
  } else if (t < 14464) {
    w3s[t - 14432] = W3[t - 14432] * LN2;
  }
}

// ------------------------------ main kernel --------------------------------
__global__ __launch_bounds__(NT, 8)
void tb_fused(const float* __restrict__ core, const float* __restrict__ ligs,
              const float* __restrict__ b3,   const char* __restrict__ ws,
              float* __restrict__ out)
{
  extern __shared__ char smem[];
  const int tid  = (int)threadIdx.x;
  const int lane = tid & 63;
  const int ln   = lane & 15;        // fragment column
  const int qd   = lane >> 4;        // fragment quad
  const int wv   = __builtin_amdgcn_readfirstlane(tid >> 6);  // 0..15
  const int b0   = (int)blockIdx.x * BPB;

  const uint16_t* w2t = (const uint16_t*)(ws + WS_W2T);
  const float*    b1s = (const float*)(ws + WS_B1);
  const float*    b2s = (const float*)(ws + WS_B2);
  const float*    w3s = (const float*)(ws + WS_W3);

  uint16_t* Ubuf = (uint16_t*)(smem + U_OFF);         // [b][n] : u/2 as f16
  float*    yred = (float*)(smem + Y_OFF);

  // ---- stage W1T (compact ws rows of 64 halves -> LDS rows of stride 72) --
  #pragma unroll
  for (int rep = 0; rep < 3; ++rep) {
    const int c   = tid + rep * NT;                   // < 3072 always
    const int row = c >> 4, col = c & 15;
    *(uint2*)(smem + WT_OFF + row * (WT_RS * 2) + col * 8) =
        *(const uint2*)(ws + WS_W1T + row * 128 + col * 8);
  }
  if (tid < BPB) yred[tid] = 0.0f;
  __syncthreads();                                    // barrier #1: W1T ready

  // ------------- Phase 1 / Pass A: u rows (8 waves, one (mt,nt) each) -----
  // u = core@W1slab0 + b1 ; store u/2 (f16) to Ubuf[b][n]
  if (wv < 8) {
    const int mt = wv & 1;
    const int nt = wv >> 1;                           // 0..3
    const float* srcC = core + (size_t)(b0 + mt * 16 + ln) * 64;
    union AF { f16x8 v; fp16v2 p[4]; } Ac[2];
    #pragma unroll
    for (int ks = 0; ks < 2; ++ks) {
      const float4 c0 = *(const float4*)(srcC + ks * 32 + qd * 8);
      const float4 c1 = *(const float4*)(srcC + ks * 32 + qd * 8 + 4);
      Ac[ks].p[0] = __builtin_amdgcn_cvt_pkrtz(c0.x, c0.y);
      Ac[ks].p[1] = __builtin_amdgcn_cvt_pkrtz(c0.z, c0.w);
      Ac[ks].p[2] = __builtin_amdgcn_cvt_pkrtz(c1.x, c1.y);
      Ac[ks].p[3] = __builtin_amdgcn_cvt_pkrtz(c1.z, c1.w);
    }
    const float b1v = b1s[nt * 16 + ln];
    f32x4 cu = {b1v, b1v, b1v, b1v};
    #pragma unroll
    for (int ks = 0; ks < 2; ++ks) {
      const f16x8 B0 = *(const f16x8*)(smem + WT_OFF +
          ((nt * 16 + ln) * WT_RS + ks * 32 + qd * 8) * 2);
      cu = __builtin_amdgcn_mfma_f32_16x16x32_f16(Ac[ks].v, B0, cu, 0, 0, 0);
    }
    #pragma unroll
    for (int reg = 0; reg < 4; ++reg) {
      const int b = mt * 16 + qd * 4 + reg;
      Ubuf[b * 64 + nt * 16 + ln] =
          __half_as_ushort(__float2half(0.5f * cu[reg]));
    }
  }
  __syncthreads();                                    // barrier #2: U ready

  // ------------- Phase 1 / Pass B: a/b rows (12 waves, one (lig,mt)) ------
  // T[lig] = lig@W1slab1 + u/2 ; T[6+lig] = lig@W1slab2 + u/2
  if (wv < 12) {
    const int lg = wv >> 1;
    const int mt = wv & 1;
    const float* srcL = ligs + ((size_t)(b0 + mt * 16 + ln) * 6 + (size_t)lg) * 64;
    union AF { f16x8 v; fp16v2 p[4]; } Al[2];
    #pragma unroll
    for (int ks = 0; ks < 2; ++ks) {
      const float4 l0 = *(const float4*)(srcL + ks * 32 + qd * 8);
      const float4 l1 = *(const float4*)(srcL + ks * 32 + qd * 8 + 4);
      Al[ks].p[0] = __builtin_amdgcn_cvt_pkrtz(l0.x, l0.y);
      Al[ks].p[1] = __builtin_amdgcn_cvt_pkrtz(l0.z, l0.w);
      Al[ks].p[2] = __builtin_amdgcn_cvt_pkrtz(l1.x, l1.y);
      Al[ks].p[3] = __builtin_amdgcn_cvt_pkrtz(l1.z, l1.w);
    }
    #pragma unroll 2
    for (int nt = 0; nt < 4; ++nt) {
      f32x4 ca = {0.f, 0.f, 0.f, 0.f};
      f32x4 cb = {0.f, 0.f, 0.f, 0.f};
      #pragma unroll
      for (int ks = 0; ks < 2; ++ks) {
        const int rb = (nt * 16 + ln) * WT_RS + ks * 32 + qd * 8;
        const f16x8 B1 = *(const f16x8*)(smem + WT_OFF + (rb +  64 * WT_RS) * 2);
        const f16x8 B2 = *(const f16x8*)(smem + WT_OFF + (rb + 128 * WT_RS) * 2);
        ca = __builtin_amdgcn_mfma_f32_16x16x32_f16(Al[ks].v, B1, ca, 0, 0, 0);
        cb = __builtin_amdgcn_mfma_f32_16x16x32_f16(Al[ks].v, B2, cb, 0, 0, 0);
      }
      #pragma unroll
      for (int reg = 0; reg < 4; ++reg) {
        const int b = mt * 16 + qd * 4 + reg;
        const float uh = __half2float(
            __ushort_as_half(Ubuf[b * 64 + nt * 16 + ln]));
        char* Tbb = smem + (size_t)b * T_STRIDE + (nt * 16 + ln) * 2;
        *(uint16_t*)(Tbb + lg * 128)       = __half_as_ushort(__float2half(ca[reg] + uh));
        *(uint16_t*)(Tbb + (6 + lg) * 128) = __half_as_ushort(__float2half(cb[reg] + uh));
      }
    }
  }

  // W2 B-frags + epilogue consts (global, L2-hot) — overlaps Pass-B tail
  f16x8 W2f[2][2];
  #pragma unroll
  for (int nt = 0; nt < 2; ++nt)
    #pragma unroll
    for (int ks = 0; ks < 2; ++ks)
      W2f[nt][ks] = *(const f16x8*)(w2t + (nt * 16 + ln) * 64 + ks * 32 + qd * 8);
  float b2v[2];
  b2v[0] = b2s[ln];
  b2v[1] = b2s[16 + ln];
  __half2 w3pk = __floats2half2_rn(w3s[ln], w3s[16 + ln]);

  __syncthreads();                                    // barrier #3: T ready

  // ------------- Phase 2: 60 units (30 q x 2 mt) over 16 waves ------------
  const int mtw = wv & 1;
  const int qr  = wv >> 1;                            // 0..7
  const __half2 one2  = __float2half2_rn(1.0f);
  const __half2 zero2 = __float2half2_rn(0.0f);
  const char* Tb  = smem + (size_t)(mtw * 16 + ln) * T_STRIDE;
  const int koff  = qd * 16;

  union U4 { u32x4 u; __half2 h[4]; };
  float yacc[4] = {0.f, 0.f, 0.f, 0.f};

  #pragma unroll
  for (int t3 = 0; t3 < 4; ++t3) {
    const int q = qr + 8 * t3;                        // <= 31
    const __half2 w3h = (q < 30) ? w3pk : zero2;      // wave-uniform mask
    const int p  = q >> 1;
    const int iv = (int)((I_BITS >> (3 * p)) & 7ull); // p=15 -> 0 (safe)
    const int jv = (int)((J_BITS >> (3 * p)) & 7ull);
    const int rA = ((q & 1) ? jv : iv) * 128;
    const int rB = (6 + ((q & 1) ? iv : jv)) * 128;

    U4 a0, a1, bb0, bb1;
    a0.u  = *(const u32x4*)(Tb + rA + koff);
    a1.u  = *(const u32x4*)(Tb + rA + 64 + koff);
    bb0.u = *(const u32x4*)(Tb + rB + koff);
    bb1.u = *(const u32x4*)(Tb + rB + 64 + koff);

    union { f16x8 v; __half2 h[4]; } A0, A1;
    #pragma unroll
    for (int w = 0; w < 4; ++w) A0.h[w] = h1pair(a0.h[w], bb0.h[w], one2);
    #pragma unroll
    for (int w = 0; w < 4; ++w) A1.h[w] = h1pair(a1.h[w], bb1.h[w], one2);

    f32x4 c0 = {b2v[0], b2v[0], b2v[0], b2v[0]};      // b2 folded into C-init
    f32x4 c1 = {b2v[1], b2v[1], b2v[1], b2v[1]};
    c0 = __builtin_amdgcn_mfma_f32_16x16x32_f16(A0.v, W2f[0][0], c0, 0, 0, 0);
    c0 = __builtin_amdgcn_mfma_f32_16x16x32_f16(A1.v, W2f[0][1], c0, 0, 0, 0);
    c1 = __builtin_amdgcn_mfma_f32_16x16x32_f16(A0.v, W2f[1][0], c1, 0, 0, 0);
    c1 = __builtin_amdgcn_mfma_f32_16x16x32_f16(A1.v, W2f[1][1], c1, 0, 0, 0);

    #pragma unroll
    for (int reg = 0; reg < 4; ++reg)
      yacc[reg] = dot2(sp2pk(c0[reg], c1[reg], one2), w3h, yacc[reg]);
  }

  // reduce over the 16 fragment columns (ln) inside each quad group
  #pragma unroll
  for (int reg = 0; reg < 4; ++reg) {
    float v = yacc[reg];
    v += __shfl_xor(v, 1);
    v += __shfl_xor(v, 2);
    v += __shfl_xor(v, 4);
    v += __shfl_xor(v, 8);
    yacc[reg] = v;
  }
  if (ln == 0) {
    #pragma unroll
    for (int reg = 0; reg < 4; ++reg)
      atomicAdd(&yred[mtw * 16 + qd * 4 + reg], yacc[reg]);
  }
  __syncthreads();
  if (tid < BPB) out[b0 + tid] = 0.5f * yred[tid] + 15.0f * b3[0];
}

extern "C" void kernel_launch(void* const* d_in, const int* in_sizes, int n_in,
                              void* d_out, int out_size, void* d_ws, size_t ws_size,
                              hipStream_t stream) {
  const float* core = (const float*)d_in[0];
  const float* ligs = (const float*)d_in[1];
  const float* W1   = (const float*)d_in[2];
  const float* b1   = (const float*)d_in[3];
  const float* W2   = (const float*)d_in[4];
  const float* b2   = (const float*)d_in[5];
  const float* W3   = (const float*)d_in[6];
  const float* b3   = (const float*)d_in[7];
  float* out = (float*)d_out;
  char*  ws  = (char*)d_ws;                 // needs WS_BYTES (29 KB) scratch

  const int B = in_sizes[0] / 64;           // 32768
  const int grid = B / BPB;                 // 1024

  prep<<<dim3(57), dim3(256), 0, stream>>>(W1, b1, W2, b2, W3, ws);

  (void)hipFuncSetAttribute((const void*)tb_fused,
                            hipFuncAttributeMaxDynamicSharedMemorySize, LDS_BYTES);
  tb_fused<<<dim3(grid), dim3(NT), LDS_BYTES, stream>>>(
      core, ligs, b3, ws, out);
}